// Round 8
// baseline (138.176 us; speedup 1.0000x reference)
//
#include <hip/hip_runtime.h>
#include <hip/hip_bf16.h>

#define TROWS 1048576
#define RPB   512                    // rows per block (2 original chunks)
#define NBLK  (TROWS / RPB)          // 2048
#define LSTRIDE 36                   // out0 LDS row stride in shorts (72 B)

typedef float f32x4  __attribute__((ext_vector_type(4)));
typedef short bf16x8 __attribute__((ext_vector_type(8)));
typedef short bf16x4 __attribute__((ext_vector_type(4)));

#define MFMA(a, b, c) __builtin_amdgcn_mfma_f32_16x16x32_bf16(a, b, c, 0, 0, 0)

__device__ __forceinline__ short f2bf(float v) {
    __hip_bfloat16 b = __float2bfloat16(v);
    return __builtin_bit_cast(short, b);
}
__device__ __forceinline__ float bf2f(short s) {
    unsigned u = ((unsigned)(unsigned short)s) << 16;
    return __builtin_bit_cast(float, u);
}

// k-map for ALL A/B fragments: kappa(g,j) = j<4 ? 4g+j : 16+4g+(j-4)
// ---------------------------------------------------------------------------
// Prep: weights -> bf16 fragment order (verified rounds 2-7).
//   W0a: frag 0..15 (ks*8+nt)   W0b: 16..23 (k2*2+ot)
//   W1a: 24..47 (ks*8+nt)       W1b: 48..55 (k2*2+ot)
// ---------------------------------------------------------------------------
__global__ __launch_bounds__(64) void prep_kernel(
    const float* __restrict__ W0a, const float* __restrict__ W0b,
    const float* __restrict__ W1a, const float* __restrict__ W1b,
    bf16x8* __restrict__ frag)
{
    const int fid = blockIdx.x, l = threadIdx.x, c = l & 15, g = l >> 4;
    const float* W; int N, ks, nt;
    if (fid < 16)      { W = W0a; N = 128; ks = fid >> 3;        nt = fid & 7; }
    else if (fid < 24) { W = W0b; N = 32;  ks = (fid - 16) >> 1; nt = (fid - 16) & 1; }
    else if (fid < 48) { W = W1a; N = 128; ks = (fid - 24) >> 3; nt = (fid - 24) & 7; }
    else               { W = W1b; N = 32;  ks = (fid - 48) >> 1; nt = (fid - 48) & 1; }
    bf16x8 f;
    #pragma unroll
    for (int j = 0; j < 8; ++j) {
        const int k = 32 * ks + ((j < 4) ? (4 * g + j) : (16 + 4 * g + (j - 4)));
        f[j] = f2bf(W[k * N + 16 * nt + c]);
    }
    frag[fid * 64 + l] = f;
}

// ---------------------------------------------------------------------------
// Fused kernel: 8 waves / 512 rows per block. Weight frags staged in LDS
// (W0 24KB phase A -> W1 32KB phase B, same region). W1 frags prefetched to
// registers after B1 (T14) so only the ds_write sits between B2/B3.
// ---------------------------------------------------------------------------
__global__ __launch_bounds__(512, 2) void fused_kernel(
    const float* __restrict__ x, const int* __restrict__ topk,
    const float* __restrict__ wts,
    const float* __restrict__ b0a, const float* __restrict__ b0b,
    const float* __restrict__ b1a, const float* __restrict__ b1b,
    const bf16x8* __restrict__ frag,
    float* __restrict__ out)
{
    const int b = blockIdx.x;
    const int bb = b * RPB;
    const int tid = threadIdx.x, wv = tid >> 6, l = tid & 63, c = l & 15, g = l >> 4;

    __shared__ __align__(16) short frag_lds[32 * 64 * 8];    // 32 KB
    __shared__ __align__(16) short out0_lds[513 * LSTRIDE];  // 36.9 KB
    __shared__ int wtot[8];

    #define LDSF(fl) (*(const bf16x8*)&frag_lds[(((fl) * 64) + l) * 8])

    // --- stage W0 frags (fid 0..23 -> local 0..23): 24KB, 3 x 16B/thread ---
    #pragma unroll
    for (int i = 0; i < 3; ++i) {
        const int e = tid + i * 512;      // e < 1536
        *(f32x4*)&frag_lds[e * 8] = *(const f32x4*)&frag[e];
    }

    // --- own-row inclusive wave cummax of (mask0 ? t : 0) ---
    const int t = bb + tid;
    const int2 tko = ((const int2*)topk)[t];
    const bool m0o = (tko.x == 0) || (tko.y == 0);
    int s = m0o ? t : 0;
    #pragma unroll
    for (int off = 1; off < 64; off <<= 1) {
        int u = __shfl_up(s, off, 64);
        if (l >= off) s = max(s, u);
    }
    if (l == 63) wtot[wv] = s;

    // --- backward scan for p = last mask0 row < bb (input-only) ---
    int p = 0;
    for (int base = bb - 64; base >= 0; base -= 64) {
        const int2 tkq = ((const int2*)topk)[base + l];
        const bool mm = (tkq.x == 0) || (tkq.y == 0);
        const unsigned long long bal = __ballot(mm);
        if (bal) { p = base + 63 - __clzll(bal); break; }
    }
    const int2 tkp = ((const int2*)topk)[p];
    const bool m0p = (tkp.x == 0) || (tkp.y == 0);

    // --- x fragments: own 4 tiles (+ p-row on wave 7), the only x reads ---
    bf16x8 xf[4][2];
    #pragma unroll
    for (int rt = 0; rt < 4; ++rt) {
        const int row = bb + wv * 64 + rt * 16 + c;
        const float* xr = x + (size_t)row * 64;
        #pragma unroll
        for (int ks = 0; ks < 2; ++ks) {
            f32x4 a  = *(const f32x4*)(xr + 32 * ks + 4 * g);
            f32x4 b2 = *(const f32x4*)(xr + 32 * ks + 16 + 4 * g);
            #pragma unroll
            for (int j = 0; j < 4; ++j) { xf[rt][ks][j] = f2bf(a[j]); xf[rt][ks][4 + j] = f2bf(b2[j]); }
        }
    }
    bf16x8 xfp[2];
    if (wv == 7) {
        const float* xp = x + (size_t)p * 64;
        #pragma unroll
        for (int ks = 0; ks < 2; ++ks) {
            f32x4 a  = *(const f32x4*)(xp + 32 * ks + 4 * g);
            f32x4 b2 = *(const f32x4*)(xp + 32 * ks + 16 + 4 * g);
            #pragma unroll
            for (int j = 0; j < 4; ++j) { xfp[ks][j] = f2bf(a[j]); xfp[ks][4 + j] = f2bf(b2[j]); }
        }
    }

    __syncthreads();   // B1: W0 staged; wtot visible

    // --- T14: issue W1 frag loads NOW (consumed after B2; hides L2 latency
    //     under phase A). 32KB = 2048 x 16B, 4 per thread. ---
    f32x4 w1pre[4];
    #pragma unroll
    for (int i = 0; i < 4; ++i)
        w1pre[i] = *(const f32x4*)&frag[24 * 64 + tid + i * 512];

    // --- per-row global inclusive cummax ---
    int pre = 0;
    #pragma unroll
    for (int w2 = 0; w2 < 8; ++w2)
        if (w2 < wv) pre = max(pre, wtot[w2]);
    const int s_full = max(pre, s);

    // ---- phase A: MLP0, k2-outer (frags ds_read once, 4 tiles share) ----
    f32x4 acc2a[4][2];
    {
        f32x4 bi0 = *(const f32x4*)(b0b + 4 * g);
        f32x4 bi1 = *(const f32x4*)(b0b + 16 + 4 * g);
        #pragma unroll
        for (int rt = 0; rt < 4; ++rt) { acc2a[rt][0] = bi0; acc2a[rt][1] = bi1; }
    }
    #pragma unroll
    for (int k2 = 0; k2 < 4; ++k2) {
        const bf16x8 fa00 = LDSF(0 * 8 + 2 * k2 + 0);
        const bf16x8 fa01 = LDSF(0 * 8 + 2 * k2 + 1);
        const bf16x8 fa10 = LDSF(1 * 8 + 2 * k2 + 0);
        const bf16x8 fa11 = LDSF(1 * 8 + 2 * k2 + 1);
        const bf16x8 fb0  = LDSF(16 + 2 * k2 + 0);
        const bf16x8 fb1  = LDSF(16 + 2 * k2 + 1);
        const f32x4 bi0 = *(const f32x4*)(b0a + 16 * (2 * k2 + 0) + 4 * g);
        const f32x4 bi1 = *(const f32x4*)(b0a + 16 * (2 * k2 + 1) + 4 * g);
        #pragma unroll
        for (int rt = 0; rt < 4; ++rt) {
            f32x4 a10 = bi0, a11 = bi1;
            a10 = MFMA(fa00, xf[rt][0], a10);
            a10 = MFMA(fa10, xf[rt][1], a10);
            a11 = MFMA(fa01, xf[rt][0], a11);
            a11 = MFMA(fa11, xf[rt][1], a11);
            bf16x8 hf;
            #pragma unroll
            for (int j = 0; j < 8; ++j)
                hf[j] = f2bf(fmaxf((j < 4 ? a10 : a11)[j & 3], 0.0f));
            acc2a[rt][0] = MFMA(fb0, hf, acc2a[rt][0]);
            acc2a[rt][1] = MFMA(fb1, hf, acc2a[rt][1]);
        }
    }

    // --- store own tiles (masked) to out0 LDS ---
    #pragma unroll
    for (int rt = 0; rt < 4; ++rt) {
        const int slot = wv * 64 + rt * 16 + c;
        const int2 tk = ((const int2*)topk)[bb + slot];
        const bool m0 = (tk.x == 0) || (tk.y == 0);
        #pragma unroll
        for (int ot = 0; ot < 2; ++ot) {
            bf16x4 v;
            #pragma unroll
            for (int j = 0; j < 4; ++j) v[j] = f2bf(m0 ? acc2a[rt][ot][j] : 0.0f);
            *(bf16x4*)(&out0_lds[slot * LSTRIDE + 16 * ot + 4 * g]) = v;
        }
    }

    // --- wave 7: p-row tile -> slot 512 ---
    if (wv == 7) {
        f32x4 accp[2];
        accp[0] = *(const f32x4*)(b0b + 4 * g);
        accp[1] = *(const f32x4*)(b0b + 16 + 4 * g);
        #pragma unroll
        for (int k2 = 0; k2 < 4; ++k2) {
            const bf16x8 fa00 = LDSF(0 * 8 + 2 * k2 + 0);
            const bf16x8 fa01 = LDSF(0 * 8 + 2 * k2 + 1);
            const bf16x8 fa10 = LDSF(1 * 8 + 2 * k2 + 0);
            const bf16x8 fa11 = LDSF(1 * 8 + 2 * k2 + 1);
            const bf16x8 fb0  = LDSF(16 + 2 * k2 + 0);
            const bf16x8 fb1  = LDSF(16 + 2 * k2 + 1);
            f32x4 a10 = *(const f32x4*)(b0a + 16 * (2 * k2 + 0) + 4 * g);
            f32x4 a11 = *(const f32x4*)(b0a + 16 * (2 * k2 + 1) + 4 * g);
            a10 = MFMA(fa00, xfp[0], a10);
            a10 = MFMA(fa10, xfp[1], a10);
            a11 = MFMA(fa01, xfp[0], a11);
            a11 = MFMA(fa11, xfp[1], a11);
            bf16x8 hf;
            #pragma unroll
            for (int j = 0; j < 8; ++j)
                hf[j] = f2bf(fmaxf((j < 4 ? a10 : a11)[j & 3], 0.0f));
            accp[0] = MFMA(fb0, hf, accp[0]);
            accp[1] = MFMA(fb1, hf, accp[1]);
        }
        if (c == 0) {
            #pragma unroll
            for (int ot = 0; ot < 2; ++ot) {
                bf16x4 v;
                #pragma unroll
                for (int j = 0; j < 4; ++j) v[j] = f2bf(m0p ? accp[ot][j] : 0.0f);
                *(bf16x4*)(&out0_lds[512 * LSTRIDE + 16 * ot + 4 * g]) = v;
            }
        }
    }

    __syncthreads();   // B2: out0 complete; all W0 frag reads done

    // --- write W1 frags from registers (loads long since landed) ---
    #pragma unroll
    for (int i = 0; i < 4; ++i)
        *(f32x4*)&frag_lds[(tid + i * 512) * 8] = w1pre[i];

    __syncthreads();   // B3: W1 frags staged

    // --- gather filled frags via s_full ---
    bf16x8 xf2[4];
    #pragma unroll
    for (int rt = 0; rt < 4; ++rt) {
        const int sF = __shfl(s_full, rt * 16 + c, 64);
        const int slot = (sF > 0) ? (sF - bb) : 512;
        const short* fr = &out0_lds[slot * LSTRIDE];
        bf16x4 fa_ = *(const bf16x4*)(fr + 4 * g);
        bf16x4 fb_ = *(const bf16x4*)(fr + 16 + 4 * g);
        #pragma unroll
        for (int j = 0; j < 4; ++j) { xf2[rt][j] = fa_[j]; xf2[rt][4 + j] = fb_[j]; }
    }

    // ---- phase B: MLP1, k2-outer ----
    f32x4 acc2b[4][2];
    {
        f32x4 bi0 = *(const f32x4*)(b1b + 4 * g);
        f32x4 bi1 = *(const f32x4*)(b1b + 16 + 4 * g);
        #pragma unroll
        for (int rt = 0; rt < 4; ++rt) { acc2b[rt][0] = bi0; acc2b[rt][1] = bi1; }
    }
    #pragma unroll
    for (int k2 = 0; k2 < 4; ++k2) {
        const bf16x8 fa00 = LDSF(0 * 8 + 2 * k2 + 0);   // W1a local 0..23
        const bf16x8 fa01 = LDSF(0 * 8 + 2 * k2 + 1);
        const bf16x8 fa10 = LDSF(1 * 8 + 2 * k2 + 0);
        const bf16x8 fa11 = LDSF(1 * 8 + 2 * k2 + 1);
        const bf16x8 fa20 = LDSF(2 * 8 + 2 * k2 + 0);
        const bf16x8 fa21 = LDSF(2 * 8 + 2 * k2 + 1);
        const bf16x8 fb0  = LDSF(24 + 2 * k2 + 0);      // W1b local 24..31
        const bf16x8 fb1  = LDSF(24 + 2 * k2 + 1);
        const f32x4 bi0 = *(const f32x4*)(b1a + 16 * (2 * k2 + 0) + 4 * g);
        const f32x4 bi1 = *(const f32x4*)(b1a + 16 * (2 * k2 + 1) + 4 * g);
        #pragma unroll
        for (int rt = 0; rt < 4; ++rt) {
            f32x4 a10 = bi0, a11 = bi1;
            a10 = MFMA(fa00, xf[rt][0], a10);
            a10 = MFMA(fa10, xf[rt][1], a10);
            a10 = MFMA(fa20, xf2[rt], a10);
            a11 = MFMA(fa01, xf[rt][0], a11);
            a11 = MFMA(fa11, xf[rt][1], a11);
            a11 = MFMA(fa21, xf2[rt], a11);
            bf16x8 hf;
            #pragma unroll
            for (int j = 0; j < 8; ++j)
                hf[j] = f2bf(fmaxf((j < 4 ? a10 : a11)[j & 3], 0.0f));
            acc2b[rt][0] = MFMA(fb0, hf, acc2b[rt][0]);
            acc2b[rt][1] = MFMA(fb1, hf, acc2b[rt][1]);
        }
    }

    // --- blend + store ---
    #pragma unroll
    for (int rt = 0; rt < 4; ++rt) {
        const int slot = wv * 64 + rt * 16 + c;
        const int row = bb + slot;
        const int2 tk = ((const int2*)topk)[row];
        const bool m1 = (tk.x == 1) || (tk.y == 1);
        const float w  = wts[(size_t)row * 2];
        const float wc = 1.0f - w;
        #pragma unroll
        for (int ot = 0; ot < 2; ++ot) {
            bf16x4 oa = *(const bf16x4*)(&out0_lds[slot * LSTRIDE + 16 * ot + 4 * g]);
            f32x4 r;
            #pragma unroll
            for (int j = 0; j < 4; ++j) {
                const float e1 = m1 ? acc2b[rt][ot][j] : 0.0f;
                r[j] = w * bf2f(oa[j]) + wc * e1;
            }
            *(f32x4*)(out + (size_t)row * 32 + 16 * ot + 4 * g) = r;
        }
    }
    #undef LDSF
}

// ---------------------------------------------------------------------------
extern "C" void kernel_launch(void* const* d_in, const int* in_sizes, int n_in,
                              void* d_out, int out_size, void* d_ws, size_t ws_size,
                              hipStream_t stream)
{
    const float* x    = (const float*)d_in[0];
    const int*   topk = (const int*)  d_in[1];
    const float* wts  = (const float*)d_in[2];
    const float* W0a  = (const float*)d_in[3];
    const float* b0a  = (const float*)d_in[4];
    const float* W0b  = (const float*)d_in[5];
    const float* b0b  = (const float*)d_in[6];
    const float* W1a  = (const float*)d_in[7];
    const float* b1a  = (const float*)d_in[8];
    const float* W1b  = (const float*)d_in[9];
    const float* b1b  = (const float*)d_in[10];
    float* out = (float*)d_out;

    bf16x8* frag = (bf16x8*)d_ws;   // 56 KiB

    prep_kernel<<<dim3(56), dim3(64), 0, stream>>>(W0a, W0b, W1a, W1b, frag);
    fused_kernel<<<dim3(NBLK), dim3(512), 0, stream>>>(
        x, topk, wts, b0a, b0b, b1a, b1b, frag, out);
}